// Round 7
// baseline (734.310 us; speedup 1.0000x reference)
//
#include <hip/hip_runtime.h>
#include <math.h>

#define F_IN 128
#define AH 16
#define ALPHA 0.2f
#define BSTRIDE 98            // nodes per bucket (srcoff fits 7 bits)
#define PCAP 8064             // records staged in LDS per bucket (63 KB)

__device__ __forceinline__ unsigned f2bf_rn(float x) {
    unsigned u = __float_as_uint(x);
    return (u + 0x7fffu + ((u >> 16) & 1u)) >> 16;
}

// ============ K1: h_mini = input @ w_mini + b_mini  AND  sim = bf16(input*deg)
__global__ void k_mini(const float* __restrict__ input,
                       const float* __restrict__ w,
                       const float* __restrict__ b,
                       const float* __restrict__ degree,
                       float* __restrict__ out,
                       unsigned* __restrict__ sim, int n) {
    __shared__ float ws[F_IN * AH];
    __shared__ float rows[16][F_IN + 1];
    __shared__ float dgs[16];
    for (int i = threadIdx.x; i < F_IN * AH; i += blockDim.x) ws[i] = w[i];
    const int base = blockIdx.x * 16;
    for (int idx = threadIdx.x; idx < 16 * F_IN; idx += blockDim.x) {
        const int l = idx >> 7, f = idx & 127;
        const int node = base + l;
        rows[l][f] = (node < n) ? input[(size_t)node * F_IN + f] : 0.f;
    }
    if (threadIdx.x < 16) {
        const int node = base + threadIdx.x;
        dgs[threadIdx.x] = (node < n) ? degree[node] : 0.f;
    }
    __syncthreads();
    {
        const int l = threadIdx.x >> 4;
        const int j = threadIdx.x & 15;
        const int node = base + l;
        if (node < n) {
            float acc = b[j];
            #pragma unroll 8
            for (int f = 0; f < F_IN; ++f) acc += rows[l][f] * ws[f * AH + j];
            out[(size_t)node * AH + j] = acc;
        }
    }
    for (int idx = threadIdx.x; idx < 16 * 64; idx += blockDim.x) {
        const int l = idx >> 6, pr = idx & 63;
        const int node = base + l;
        if (node < n) {
            const float dg = dgs[l];
            const float x = rows[l][2 * pr]     * dg;
            const float y = rows[l][2 * pr + 1] * dg;
            sim[(size_t)node * 64 + pr] = (f2bf_rn(y) << 16) | f2bf_rn(x);
        }
    }
}

// ============ K-prep ======================================================
__global__ void k_prep(const float* __restrict__ lf1_w, const float* __restrict__ ab,
                       float* __restrict__ Cj) {
    const int j = threadIdx.x;
    if (j < AH) {
        float c = 0.f;
        for (int k = 0; k < AH; ++k)
            c += ab[k] * (lf1_w[k * AH + j] + lf1_w[(AH + k) * AH + j]);
        Cj[j] = c;
    }
}

// ============ K2: histogram of src ========================================
__global__ void k_hist(const int* __restrict__ src, int* __restrict__ cnt, int e) {
    const int i = blockIdx.x * blockDim.x + threadIdx.x;
    if (i < e) atomicAdd(&cnt[src[i]], 1);
}

// ============ K3: exclusive scan ==========================================
#define SCAN_B 256
#define SCAN_I 4
__global__ void k_scan_part(const int* __restrict__ cnt, int* __restrict__ excl,
                            int* __restrict__ bsum, int n) {
    __shared__ int sh[SCAN_B];
    const int t = threadIdx.x;
    const int base = blockIdx.x * (SCAN_B * SCAN_I) + t * SCAN_I;
    int v[SCAN_I];
    int s = 0;
    #pragma unroll
    for (int k = 0; k < SCAN_I; ++k) { const int i = base + k; v[k] = (i < n) ? cnt[i] : 0; s += v[k]; }
    sh[t] = s; __syncthreads();
    for (int off = 1; off < SCAN_B; off <<= 1) {
        const int x = (t >= off) ? sh[t - off] : 0;
        __syncthreads();
        sh[t] += x;
        __syncthreads();
    }
    int r = sh[t] - s;
    if (t == SCAN_B - 1) bsum[blockIdx.x] = sh[t];
    #pragma unroll
    for (int k = 0; k < SCAN_I; ++k) { const int i = base + k; if (i < n) excl[i] = r; r += v[k]; }
}
__global__ void k_scan_tops(int* __restrict__ bsum, int nb) {
    __shared__ int sh[SCAN_B];
    const int t = threadIdx.x;
    const int v = (t < nb) ? bsum[t] : 0;
    sh[t] = v; __syncthreads();
    for (int off = 1; off < SCAN_B; off <<= 1) {
        const int x = (t >= off) ? sh[t - off] : 0;
        __syncthreads();
        sh[t] += x;
        __syncthreads();
    }
    if (t < nb) bsum[t] = sh[t] - v;
}
__global__ void k_scan_add(int* __restrict__ excl, const int* __restrict__ bsum, int n) {
    const int i = blockIdx.x * blockDim.x + threadIdx.x;
    if (i < n) excl[i] += bsum[i >> 10];
}

// ============ K-binit: bucket bases/cursors from row offsets ==============
__global__ void k_binit(const int* __restrict__ row_ofs, int* __restrict__ bucket_base,
                        int* __restrict__ bucket_cur, int nb, int n, int e) {
    const int b = blockIdx.x * blockDim.x + threadIdx.x;
    if (b > nb) return;
    const int node = b * BSTRIDE;
    const int v = (node < n) ? row_ofs[node] : e;
    bucket_base[b] = v;
    if (b < nb) bucket_cur[b] = v;
}

// ============ K5: edge MLP, original edge order (all IO coalesced) ========
// fc0 segment-summed via atomics; fc1 stored f32 coalesced.
#define ROW4(base, val) \
    w = Wv[(base) * 4 + 0]; f0  += (val) * w.x; f1  += (val) * w.y; f2  += (val) * w.z; f3  += (val) * w.w; \
    w = Wv[(base) * 4 + 1]; f4  += (val) * w.x; f5  += (val) * w.y; f6  += (val) * w.z; f7  += (val) * w.w; \
    w = Wv[(base) * 4 + 2]; f8  += (val) * w.x; f9  += (val) * w.y; f10 += (val) * w.z; f11 += (val) * w.w; \
    w = Wv[(base) * 4 + 3]; f12 += (val) * w.x; f13 += (val) * w.y; f14 += (val) * w.z; f15 += (val) * w.w;

#define KSTEP(k, hs, hd) { \
    const float df_ = fabsf((hd) - (hs)); float4 w; \
    ROW4((k), (hs)) ROW4((16 + (k)), (hd)) ROW4((32 + (k)), df_) }

#define TAIL(j, fj) { \
    const float w2_ = lf2_w[j]; const float c_ = Cj[j]; \
    acc0 += w2_ * ((fj) > 0.f ? (fj) : ALPHA * (fj)); \
    const float v1_ = (fj) + c_; \
    acc1 += w2_ * (v1_ > 0.f ? v1_ : ALPHA * v1_); }

__global__ __launch_bounds__(256, 4)
void k_mlp(const int* __restrict__ src, const int* __restrict__ dst,
           const float* __restrict__ h,
           const float* __restrict__ lf1_w, const float* __restrict__ lf1_b,
           const float* __restrict__ lf2_w, const float* __restrict__ lf2_b,
           const float* __restrict__ Cj,
           float* __restrict__ fc0_sum, float* __restrict__ fcp, int e) {
    const int i = blockIdx.x * blockDim.x + threadIdx.x;
    if (i >= e) return;
    const int s = src[i];
    const int d = dst[i];
    const float4* __restrict__ ps = (const float4*)(h + (size_t)s * AH);
    const float4* __restrict__ pd = (const float4*)(h + (size_t)d * AH);
    const float4* __restrict__ Wv = (const float4*)lf1_w;

    float f0  = lf1_b[0],  f1  = lf1_b[1],  f2  = lf1_b[2],  f3  = lf1_b[3];
    float f4  = lf1_b[4],  f5  = lf1_b[5],  f6  = lf1_b[6],  f7  = lf1_b[7];
    float f8  = lf1_b[8],  f9  = lf1_b[9],  f10 = lf1_b[10], f11 = lf1_b[11];
    float f12 = lf1_b[12], f13 = lf1_b[13], f14 = lf1_b[14], f15 = lf1_b[15];

    float4 a, b4;
    a = ps[0]; b4 = pd[0];
    KSTEP(0,  a.x, b4.x) KSTEP(1,  a.y, b4.y) KSTEP(2,  a.z, b4.z) KSTEP(3,  a.w, b4.w)
    a = ps[1]; b4 = pd[1];
    KSTEP(4,  a.x, b4.x) KSTEP(5,  a.y, b4.y) KSTEP(6,  a.z, b4.z) KSTEP(7,  a.w, b4.w)
    a = ps[2]; b4 = pd[2];
    KSTEP(8,  a.x, b4.x) KSTEP(9,  a.y, b4.y) KSTEP(10, a.z, b4.z) KSTEP(11, a.w, b4.w)
    a = ps[3]; b4 = pd[3];
    KSTEP(12, a.x, b4.x) KSTEP(13, a.y, b4.y) KSTEP(14, a.z, b4.z) KSTEP(15, a.w, b4.w)

    float acc0 = lf2_b[0], acc1 = lf2_b[0];
    TAIL(0, f0)  TAIL(1, f1)  TAIL(2, f2)   TAIL(3, f3)
    TAIL(4, f4)  TAIL(5, f5)  TAIL(6, f6)   TAIL(7, f7)
    TAIL(8, f8)  TAIL(9, f9)  TAIL(10, f10) TAIL(11, f11)
    TAIL(12, f12) TAIL(13, f13) TAIL(14, f14) TAIL(15, f15)

    const float fc0 = 1.f / (1.f + expf(-acc0));
    const float fc1 = 1.f / (1.f + expf(-acc1));
    atomicAdd(&fc0_sum[s], fc0);
    fcp[i] = fc1;
}

// ============ K6: per-node factor (elementwise) ===========================
__global__ void k_factor(const float* __restrict__ fc0_sum, const int* __restrict__ cnt,
                         float* __restrict__ factor, int n) {
    const int i = blockIdx.x * blockDim.x + threadIdx.x;
    if (i < n) factor[i] = fc0_sum[i] / fmaxf((float)cnt[i], 1.f);
}

// ============ K-ef: ef_out in original edge order (coalesced write) =======
__global__ void k_ef(const int* __restrict__ src, const int* __restrict__ dst,
                     const float* __restrict__ factor, const float* __restrict__ fcp,
                     float* __restrict__ ef_out, int e) {
    const int i = blockIdx.x * blockDim.x + threadIdx.x;
    if (i < e) ef_out[i] = factor[src[i]] * factor[dst[i]] * fcp[i];
}

// ============ K-bin: append edge records to src-bucket regions ============
// record: low32 = dst, high32 = (srcoff << 16) | bf16(fc1)
__global__ void k_bin(const int* __restrict__ src, const int* __restrict__ dst,
                      const float* __restrict__ fcp, int* __restrict__ bucket_cur,
                      unsigned long long* __restrict__ rec, int e) {
    const int i = blockIdx.x * blockDim.x + threadIdx.x;
    if (i >= e) return;
    const int s = src[i];
    const int b = s / BSTRIDE;
    const int p = atomicAdd(&bucket_cur[b], 1);
    const unsigned hi = ((unsigned)(s - b * BSTRIDE) << 16) | f2bf_rn(fcp[i]);
    rec[p] = ((unsigned long long)hi << 32) | (unsigned)dst[i];
}

// ============ K-place: LDS-staged in-place scatter within bucket ==========
// Block b owns records [bucket_base[b], bucket_base[b+1]); every record's
// final CSR slot lies in the same range, so stage-all -> barrier -> scatter
// is hazard-free. row_ofs becomes row END offsets.
__global__ __launch_bounds__(512)
void k_place(const int* __restrict__ bucket_base, int* __restrict__ row_ofs,
             unsigned long long* __restrict__ rec) {
    __shared__ unsigned long long lds[PCAP];
    const int b = blockIdx.x;
    const int start = bucket_base[b];
    const int count = bucket_base[b + 1] - start;
    const int m = count < PCAP ? count : PCAP;
    for (int k = threadIdx.x; k < m; k += 512) lds[k] = rec[start + k];
    __syncthreads();
    for (int k = threadIdx.x; k < count; k += 512) {
        const unsigned long long r = (k < PCAP) ? lds[k] : rec[start + k];
        const unsigned hi = (unsigned)(r >> 32);
        const int s = b * BSTRIDE + (int)((hi >> 16) & 127u);
        const int p = atomicAdd(&row_ofs[s], 1);
        rec[p] = r;
    }
}

// ============ K7: fused SpMM + final combine (no scattered writes) ========
__global__ void k_spmm_final(const int* __restrict__ row_end, const int* __restrict__ cnt,
                             const unsigned long long* __restrict__ rec,
                             const float* __restrict__ factor,
                             const unsigned* __restrict__ sim,
                             const float* __restrict__ input,
                             const float* __restrict__ degree,
                             const float* __restrict__ adj_row,
                             float* __restrict__ out_h, int n) {
    __shared__ float2 sh[256];            // per-wave 64-entry slot: (ef, bits(dst))
    const int wid  = (blockIdx.x * blockDim.x + threadIdx.x) >> 6;
    const int lane = threadIdx.x & 63;
    const int sbase = threadIdx.x & ~63;
    if (wid >= n) return;
    const int end = row_end[wid];
    const int beg = end - cnt[wid];
    const float fnode = factor[wid];
    float acc0 = 0.f, acc1 = 0.f, efl = 0.f;
    for (int base = beg; base < end; base += 64) {
        const int rem = end - base;
        const int mm = rem < 64 ? rem : 64;
        float ef = 0.f; int dl = 0;
        if (lane < mm) {
            const unsigned long long r = rec[base + lane];
            const int d = (int)(unsigned)r;
            const float fc1 = __uint_as_float(((unsigned)(r >> 32) & 0xffffu) << 16);
            ef = fnode * factor[d] * fc1;
            dl = d;
        }
        efl += ef;
        sh[sbase + lane] = make_float2(ef, __int_as_float(dl));
        for (int j = 0; j < mm; j += 8) {
            float2 t0 = sh[sbase + j + 0];
            float2 t1 = sh[sbase + j + 1];
            float2 t2 = sh[sbase + j + 2];
            float2 t3 = sh[sbase + j + 3];
            float2 t4 = sh[sbase + j + 4];
            float2 t5 = sh[sbase + j + 5];
            float2 t6 = sh[sbase + j + 6];
            float2 t7 = sh[sbase + j + 7];
            const unsigned u0 = sim[(size_t)__float_as_int(t0.y) * 64 + lane];
            const unsigned u1 = sim[(size_t)__float_as_int(t1.y) * 64 + lane];
            const unsigned u2 = sim[(size_t)__float_as_int(t2.y) * 64 + lane];
            const unsigned u3 = sim[(size_t)__float_as_int(t3.y) * 64 + lane];
            const unsigned u4 = sim[(size_t)__float_as_int(t4.y) * 64 + lane];
            const unsigned u5 = sim[(size_t)__float_as_int(t5.y) * 64 + lane];
            const unsigned u6 = sim[(size_t)__float_as_int(t6.y) * 64 + lane];
            const unsigned u7 = sim[(size_t)__float_as_int(t7.y) * 64 + lane];
            acc0 += t0.x * __uint_as_float(u0 << 16);
            acc1 += t0.x * __uint_as_float(u0 & 0xffff0000u);
            acc0 += t1.x * __uint_as_float(u1 << 16);
            acc1 += t1.x * __uint_as_float(u1 & 0xffff0000u);
            acc0 += t2.x * __uint_as_float(u2 << 16);
            acc1 += t2.x * __uint_as_float(u2 & 0xffff0000u);
            acc0 += t3.x * __uint_as_float(u3 << 16);
            acc1 += t3.x * __uint_as_float(u3 & 0xffff0000u);
            acc0 += t4.x * __uint_as_float(u4 << 16);
            acc1 += t4.x * __uint_as_float(u4 & 0xffff0000u);
            acc0 += t5.x * __uint_as_float(u5 << 16);
            acc1 += t5.x * __uint_as_float(u5 & 0xffff0000u);
            acc0 += t6.x * __uint_as_float(u6 << 16);
            acc1 += t6.x * __uint_as_float(u6 & 0xffff0000u);
            acc0 += t7.x * __uint_as_float(u7 << 16);
            acc1 += t7.x * __uint_as_float(u7 & 0xffff0000u);
        }
    }
    for (int off = 32; off > 0; off >>= 1) efl += __shfl_xor(efl, off);
    const float aggr = efl / adj_row[wid];
    const float dg = degree[wid];
    const float2 inn = *(const float2*)(input + (size_t)wid * F_IN + 2 * lane);
    float2 o;
    o.x = acc0 * dg + (1.f - aggr) * inn.x;
    o.y = acc1 * dg + (1.f - aggr) * inn.y;
    *(float2*)(out_h + (size_t)wid * F_IN + 2 * lane) = o;
}

extern "C" void kernel_launch(void* const* d_in, const int* in_sizes, int n_in,
                              void* d_out, int out_size, void* d_ws, size_t ws_size,
                              hipStream_t stream) {
    const float* input   = (const float*)d_in[0];
    const int*   edges   = (const int*)  d_in[1];
    const float* adj_row = (const float*)d_in[3];
    const float* degree  = (const float*)d_in[4];
    const float* w_mini  = (const float*)d_in[5];
    const float* b_mini  = (const float*)d_in[6];
    const float* ab      = (const float*)d_in[7];
    const float* lf1_w   = (const float*)d_in[8];
    const float* lf1_b   = (const float*)d_in[9];
    const float* lf2_w   = (const float*)d_in[10];
    const float* lf2_b   = (const float*)d_in[11];

    const int N = in_sizes[0] / F_IN;
    const int E = in_sizes[1] / 2;
    const int NB = (N + BSTRIDE - 1) / BSTRIDE;
    const int* src = edges;
    const int* dst = edges + E;

    float* final_h = (float*)d_out;
    float* ef_out  = (float*)d_out + (size_t)N * F_IN;

    // workspace layout (4-byte words; ~53 MB total)
    float* h_mini      = (float*)d_ws;                     // N*16
    float* fcp         = h_mini + (size_t)N * AH;          // E (fc1, f32)
    float* factor      = fcp + E;                          // N
    float* fc0_sum     = factor + N;                       // N  \ memset
    int*   cnt         = (int*)(fc0_sum + N);              // N  / together
    int*   row_ofs     = cnt + N;                          // N (starts -> ends)
    float* Cj          = (float*)(row_ofs + N);            // 16
    int*   bsum        = (int*)(Cj + 16);                  // 1024
    int*   bucket_base = bsum + 1024;                      // NB+1
    int*   bucket_cur  = bucket_base + NB + 1;             // NB
    unsigned long long* rec =
        (unsigned long long*)((((uintptr_t)(bucket_cur + NB)) + 7) & ~(uintptr_t)7); // E
    unsigned* sim      = (unsigned*)(rec + E);             // N*64 bf16 pairs

    hipMemsetAsync(fc0_sum, 0, (size_t)2 * N * sizeof(float), stream);

    k_mini<<<(N + 15) / 16, 256, 0, stream>>>(input, w_mini, b_mini, degree, h_mini, sim, N);
    k_prep<<<1, 64, 0, stream>>>(lf1_w, ab, Cj);
    k_hist<<<(E + 255) / 256, 256, 0, stream>>>(src, cnt, E);
    {
        const int nb = (N + SCAN_B * SCAN_I - 1) / (SCAN_B * SCAN_I);
        k_scan_part<<<nb, SCAN_B, 0, stream>>>(cnt, row_ofs, bsum, N);
        k_scan_tops<<<1, SCAN_B, 0, stream>>>(bsum, nb);
        k_scan_add<<<(N + 255) / 256, 256, 0, stream>>>(row_ofs, bsum, N);
    }
    k_binit<<<(NB + 256) / 256, 256, 0, stream>>>(row_ofs, bucket_base, bucket_cur, NB, N, E);
    k_mlp<<<(E + 255) / 256, 256, 0, stream>>>(src, dst, h_mini,
                                               lf1_w, lf1_b, lf2_w, lf2_b, Cj,
                                               fc0_sum, fcp, E);
    k_factor<<<(N + 255) / 256, 256, 0, stream>>>(fc0_sum, cnt, factor, N);
    k_ef<<<(E + 255) / 256, 256, 0, stream>>>(src, dst, factor, fcp, ef_out, E);
    k_bin<<<(E + 255) / 256, 256, 0, stream>>>(src, dst, fcp, bucket_cur, rec, E);
    k_place<<<NB, 512, 0, stream>>>(bucket_base, row_ofs, rec);
    k_spmm_final<<<(N * 64 + 255) / 256, 256, 0, stream>>>(row_ofs, cnt, rec, factor, sim,
                                                           input, degree, adj_row, final_h, N);
}

// Round 8
// 365.838 us; speedup vs baseline: 2.0072x; 2.0072x over previous
//
#include <hip/hip_runtime.h>
#include <math.h>

#define F_IN 128
#define AH 16
#define ALPHA 0.2f
#define NB_MAX 1024           // LDS histogram capacity (N <= 262144)
#define TILE 4096             // edges per k_part1 block
#define EPT 16                // edges per thread in k_part1

__device__ __forceinline__ unsigned f2bf_rn(float x) {
    unsigned u = __float_as_uint(x);
    return (u + 0x7fffu + ((u >> 16) & 1u)) >> 16;
}
#define LOF(u) __uint_as_float((u) << 16)
#define HIF(u) __uint_as_float((u) & 0xffff0000u)

// ============ K1: hb = bf16(input @ w_mini + b), sim = bf16(input*deg) ====
__global__ void k_mini(const float* __restrict__ input,
                       const float* __restrict__ w,
                       const float* __restrict__ b,
                       const float* __restrict__ degree,
                       unsigned short* __restrict__ hb,
                       unsigned* __restrict__ sim, int n) {
    __shared__ float ws[F_IN * AH];
    __shared__ float rows[16][F_IN + 1];
    __shared__ float dgs[16];
    for (int i = threadIdx.x; i < F_IN * AH; i += blockDim.x) ws[i] = w[i];
    const int base = blockIdx.x * 16;
    for (int idx = threadIdx.x; idx < 16 * F_IN; idx += blockDim.x) {
        const int l = idx >> 7, f = idx & 127;
        const int node = base + l;
        rows[l][f] = (node < n) ? input[(size_t)node * F_IN + f] : 0.f;
    }
    if (threadIdx.x < 16) {
        const int node = base + threadIdx.x;
        dgs[threadIdx.x] = (node < n) ? degree[node] : 0.f;
    }
    __syncthreads();
    {
        const int l = threadIdx.x >> 4;
        const int j = threadIdx.x & 15;
        const int node = base + l;
        if (node < n) {
            float acc = b[j];
            #pragma unroll 8
            for (int f = 0; f < F_IN; ++f) acc += rows[l][f] * ws[f * AH + j];
            hb[(size_t)node * AH + j] = (unsigned short)f2bf_rn(acc);
        }
    }
    for (int idx = threadIdx.x; idx < 16 * 64; idx += blockDim.x) {
        const int l = idx >> 6, pr = idx & 63;
        const int node = base + l;
        if (node < n) {
            const float dg = dgs[l];
            const float x = rows[l][2 * pr]     * dg;
            const float y = rows[l][2 * pr + 1] * dg;
            sim[(size_t)node * 64 + pr] = (f2bf_rn(y) << 16) | f2bf_rn(x);
        }
    }
}

// ============ K-prep ======================================================
__global__ void k_prep(const float* __restrict__ lf1_w, const float* __restrict__ ab,
                       float* __restrict__ Cj) {
    const int j = threadIdx.x;
    if (j < AH) {
        float c = 0.f;
        for (int k = 0; k < AH; ++k)
            c += ab[k] * (lf1_w[k * AH + j] + lf1_w[(AH + k) * AH + j]);
        Cj[j] = c;
    }
}

// ============ K2: histogram of src ========================================
__global__ void k_hist(const int* __restrict__ src, int* __restrict__ cnt, int e) {
    const int i = blockIdx.x * blockDim.x + threadIdx.x;
    if (i < e) atomicAdd(&cnt[src[i]], 1);
}

// ============ K3: exclusive scan ==========================================
#define SCAN_B 256
#define SCAN_I 4
__global__ void k_scan_part(const int* __restrict__ cnt, int* __restrict__ excl,
                            int* __restrict__ bsum, int n) {
    __shared__ int sh[SCAN_B];
    const int t = threadIdx.x;
    const int base = blockIdx.x * (SCAN_B * SCAN_I) + t * SCAN_I;
    int v[SCAN_I];
    int s = 0;
    #pragma unroll
    for (int k = 0; k < SCAN_I; ++k) { const int i = base + k; v[k] = (i < n) ? cnt[i] : 0; s += v[k]; }
    sh[t] = s; __syncthreads();
    for (int off = 1; off < SCAN_B; off <<= 1) {
        const int x = (t >= off) ? sh[t - off] : 0;
        __syncthreads();
        sh[t] += x;
        __syncthreads();
    }
    int r = sh[t] - s;
    if (t == SCAN_B - 1) bsum[blockIdx.x] = sh[t];
    #pragma unroll
    for (int k = 0; k < SCAN_I; ++k) { const int i = base + k; if (i < n) excl[i] = r; r += v[k]; }
}
__global__ void k_scan_tops(int* __restrict__ bsum, int nb) {
    __shared__ int sh[SCAN_B];
    const int t = threadIdx.x;
    const int v = (t < nb) ? bsum[t] : 0;
    sh[t] = v; __syncthreads();
    for (int off = 1; off < SCAN_B; off <<= 1) {
        const int x = (t >= off) ? sh[t - off] : 0;
        __syncthreads();
        sh[t] += x;
        __syncthreads();
    }
    if (t < nb) bsum[t] = sh[t] - v;
}
__global__ void k_scan_add(int* __restrict__ excl, const int* __restrict__ bsum, int n) {
    const int i = blockIdx.x * blockDim.x + threadIdx.x;
    if (i < n) excl[i] += bsum[i >> 10];
}

// ============ K-binit: bucket bases/cursors (bucket = node>>8) ============
__global__ void k_binit(const int* __restrict__ row_ofs, int* __restrict__ bucket_base,
                        int* __restrict__ bucket_cur, int nb1, int n, int e) {
    const int b = blockIdx.x * blockDim.x + threadIdx.x;
    if (b > nb1) return;
    const int node = b << 8;
    const int v = (node < n) ? row_ofs[node] : e;
    bucket_base[b] = v;
    if (b < nb1) bucket_cur[b] = v;
}

// ============ K5: edge MLP, original order; bf16 h gathers ================
#define ROW4(base, val) \
    w = Wv[(base) * 4 + 0]; f0  += (val) * w.x; f1  += (val) * w.y; f2  += (val) * w.z; f3  += (val) * w.w; \
    w = Wv[(base) * 4 + 1]; f4  += (val) * w.x; f5  += (val) * w.y; f6  += (val) * w.z; f7  += (val) * w.w; \
    w = Wv[(base) * 4 + 2]; f8  += (val) * w.x; f9  += (val) * w.y; f10 += (val) * w.z; f11 += (val) * w.w; \
    w = Wv[(base) * 4 + 3]; f12 += (val) * w.x; f13 += (val) * w.y; f14 += (val) * w.z; f15 += (val) * w.w;

#define KSTEP(k, hs, hd) { \
    const float hs_ = (hs); const float hd_ = (hd); \
    const float df_ = fabsf(hd_ - hs_); float4 w; \
    ROW4((k), hs_) ROW4((16 + (k)), hd_) ROW4((32 + (k)), df_) }

#define TAIL(j, fj) { \
    const float w2_ = lf2_w[j]; const float c_ = Cj[j]; \
    acc0 += w2_ * ((fj) > 0.f ? (fj) : ALPHA * (fj)); \
    const float v1_ = (fj) + c_; \
    acc1 += w2_ * (v1_ > 0.f ? v1_ : ALPHA * v1_); }

__global__ __launch_bounds__(256, 4)
void k_mlp(const int* __restrict__ src, const int* __restrict__ dst,
           const unsigned short* __restrict__ hb,
           const float* __restrict__ lf1_w, const float* __restrict__ lf1_b,
           const float* __restrict__ lf2_w, const float* __restrict__ lf2_b,
           const float* __restrict__ Cj,
           float* __restrict__ fc0_sum, unsigned short* __restrict__ fcb, int e) {
    const int i = blockIdx.x * blockDim.x + threadIdx.x;
    if (i >= e) return;
    const int s = src[i];
    const int d = dst[i];
    const uint4* __restrict__ pa = (const uint4*)(hb + (size_t)s * AH);
    const uint4* __restrict__ pb = (const uint4*)(hb + (size_t)d * AH);
    const float4* __restrict__ Wv = (const float4*)lf1_w;

    float f0  = lf1_b[0],  f1  = lf1_b[1],  f2  = lf1_b[2],  f3  = lf1_b[3];
    float f4  = lf1_b[4],  f5  = lf1_b[5],  f6  = lf1_b[6],  f7  = lf1_b[7];
    float f8  = lf1_b[8],  f9  = lf1_b[9],  f10 = lf1_b[10], f11 = lf1_b[11];
    float f12 = lf1_b[12], f13 = lf1_b[13], f14 = lf1_b[14], f15 = lf1_b[15];

    const uint4 A0 = pa[0], A1 = pa[1];
    const uint4 B0 = pb[0], B1 = pb[1];
    KSTEP(0,  LOF(A0.x), LOF(B0.x)) KSTEP(1,  HIF(A0.x), HIF(B0.x))
    KSTEP(2,  LOF(A0.y), LOF(B0.y)) KSTEP(3,  HIF(A0.y), HIF(B0.y))
    KSTEP(4,  LOF(A0.z), LOF(B0.z)) KSTEP(5,  HIF(A0.z), HIF(B0.z))
    KSTEP(6,  LOF(A0.w), LOF(B0.w)) KSTEP(7,  HIF(A0.w), HIF(B0.w))
    KSTEP(8,  LOF(A1.x), LOF(B1.x)) KSTEP(9,  HIF(A1.x), HIF(B1.x))
    KSTEP(10, LOF(A1.y), LOF(B1.y)) KSTEP(11, HIF(A1.y), HIF(B1.y))
    KSTEP(12, LOF(A1.z), LOF(B1.z)) KSTEP(13, HIF(A1.z), HIF(B1.z))
    KSTEP(14, LOF(A1.w), LOF(B1.w)) KSTEP(15, HIF(A1.w), HIF(B1.w))

    float acc0 = lf2_b[0], acc1 = lf2_b[0];
    TAIL(0, f0)  TAIL(1, f1)  TAIL(2, f2)   TAIL(3, f3)
    TAIL(4, f4)  TAIL(5, f5)  TAIL(6, f6)   TAIL(7, f7)
    TAIL(8, f8)  TAIL(9, f9)  TAIL(10, f10) TAIL(11, f11)
    TAIL(12, f12) TAIL(13, f13) TAIL(14, f14) TAIL(15, f15)

    const float fc0 = 1.f / (1.f + expf(-acc0));
    const float fc1 = 1.f / (1.f + expf(-acc1));
    atomicAdd(&fc0_sum[s], fc0);
    fcb[i] = (unsigned short)f2bf_rn(fc1);
}

// ============ K6: per-node factor =========================================
__global__ void k_factor(const float* __restrict__ fc0_sum, const int* __restrict__ cnt,
                         float* __restrict__ factor, int n) {
    const int i = blockIdx.x * blockDim.x + threadIdx.x;
    if (i < n) factor[i] = fc0_sum[i] / fmaxf((float)cnt[i], 1.f);
}

// ============ K-part1: LDS-aggregated bucket partition + fused ef_out =====
// record: lo32 = dst, hi32 = (srcoff<<16) | bf16(fc1), srcoff = s & 255.
__global__ __launch_bounds__(256)
void k_part1(const int* __restrict__ src, const int* __restrict__ dst,
             const unsigned short* __restrict__ fcb,
             const float* __restrict__ factor,
             int* __restrict__ bucket_cur,
             unsigned long long* __restrict__ rec,
             float* __restrict__ ef_out, int e, int nb1) {
    __shared__ int lhist[NB_MAX];
    __shared__ int lbase[NB_MAX];
    const int t0 = blockIdx.x * TILE;
    for (int k = threadIdx.x; k < nb1; k += 256) lhist[k] = 0;
    __syncthreads();
    int sv[EPT], rv[EPT];
    #pragma unroll
    for (int k = 0; k < EPT; ++k) {
        const int i = t0 + k * 256 + threadIdx.x;
        if (i < e) {
            const int s = src[i];
            sv[k] = s;
            rv[k] = atomicAdd(&lhist[s >> 8], 1);
        } else { sv[k] = -1; rv[k] = 0; }
    }
    __syncthreads();
    for (int k = threadIdx.x; k < nb1; k += 256) {
        const int c = lhist[k];
        lbase[k] = c ? atomicAdd(&bucket_cur[k], c) : 0;
    }
    __syncthreads();
    #pragma unroll
    for (int k = 0; k < EPT; ++k) {
        const int i = t0 + k * 256 + threadIdx.x;
        if (i < e) {
            const int s = sv[k];
            const int d = dst[i];
            const unsigned fb = fcb[i];
            ef_out[i] = factor[s] * factor[d] * __uint_as_float(fb << 16);
            const unsigned hi = ((unsigned)(s & 255) << 16) | fb;
            rec[lbase[s >> 8] + rv[k]] = ((unsigned long long)hi << 32) | (unsigned)d;
        }
    }
}

// ============ K-part2: bucket -> exact CSR slots (out-of-place) ===========
__global__ __launch_bounds__(256)
void k_part2(const int* __restrict__ bucket_base, int* __restrict__ row_ofs,
             const unsigned long long* __restrict__ rec,
             unsigned long long* __restrict__ rec2) {
    const int b = blockIdx.x;
    const int start = bucket_base[b];
    const int end = bucket_base[b + 1];
    for (int k = start + (int)threadIdx.x; k < end; k += 256) {
        const unsigned long long r = rec[k];
        const int s = (b << 8) + (int)((unsigned)(r >> 48) & 255u);
        const int p = atomicAdd(&row_ofs[s], 1);
        rec2[p] = r;
    }
}

// ============ K7: fused SpMM + final combine ==============================
__global__ void k_spmm_final(const int* __restrict__ row_end, const int* __restrict__ cnt,
                             const unsigned long long* __restrict__ rec,
                             const float* __restrict__ factor,
                             const unsigned* __restrict__ sim,
                             const float* __restrict__ input,
                             const float* __restrict__ degree,
                             const float* __restrict__ adj_row,
                             float* __restrict__ out_h, int n) {
    __shared__ float2 sh[256];            // per-wave 64-entry slot: (ef, bits(dst))
    const int wid  = (blockIdx.x * blockDim.x + threadIdx.x) >> 6;
    const int lane = threadIdx.x & 63;
    const int sbase = threadIdx.x & ~63;
    if (wid >= n) return;
    const int end = row_end[wid];
    const int beg = end - cnt[wid];
    const float fnode = factor[wid];
    float acc0 = 0.f, acc1 = 0.f, efl = 0.f;
    for (int base = beg; base < end; base += 64) {
        const int rem = end - base;
        const int mm = rem < 64 ? rem : 64;
        float ef = 0.f; int dl = 0;
        if (lane < mm) {
            const unsigned long long r = rec[base + lane];
            const int d = (int)(unsigned)r;
            const float fc1 = __uint_as_float(((unsigned)(r >> 32) & 0xffffu) << 16);
            ef = fnode * factor[d] * fc1;
            dl = d;
        }
        efl += ef;
        sh[sbase + lane] = make_float2(ef, __int_as_float(dl));
        for (int j = 0; j < mm; j += 8) {
            float2 t0 = sh[sbase + j + 0];
            float2 t1 = sh[sbase + j + 1];
            float2 t2 = sh[sbase + j + 2];
            float2 t3 = sh[sbase + j + 3];
            float2 t4 = sh[sbase + j + 4];
            float2 t5 = sh[sbase + j + 5];
            float2 t6 = sh[sbase + j + 6];
            float2 t7 = sh[sbase + j + 7];
            const unsigned u0 = sim[(size_t)__float_as_int(t0.y) * 64 + lane];
            const unsigned u1 = sim[(size_t)__float_as_int(t1.y) * 64 + lane];
            const unsigned u2 = sim[(size_t)__float_as_int(t2.y) * 64 + lane];
            const unsigned u3 = sim[(size_t)__float_as_int(t3.y) * 64 + lane];
            const unsigned u4 = sim[(size_t)__float_as_int(t4.y) * 64 + lane];
            const unsigned u5 = sim[(size_t)__float_as_int(t5.y) * 64 + lane];
            const unsigned u6 = sim[(size_t)__float_as_int(t6.y) * 64 + lane];
            const unsigned u7 = sim[(size_t)__float_as_int(t7.y) * 64 + lane];
            acc0 += t0.x * __uint_as_float(u0 << 16);
            acc1 += t0.x * __uint_as_float(u0 & 0xffff0000u);
            acc0 += t1.x * __uint_as_float(u1 << 16);
            acc1 += t1.x * __uint_as_float(u1 & 0xffff0000u);
            acc0 += t2.x * __uint_as_float(u2 << 16);
            acc1 += t2.x * __uint_as_float(u2 & 0xffff0000u);
            acc0 += t3.x * __uint_as_float(u3 << 16);
            acc1 += t3.x * __uint_as_float(u3 & 0xffff0000u);
            acc0 += t4.x * __uint_as_float(u4 << 16);
            acc1 += t4.x * __uint_as_float(u4 & 0xffff0000u);
            acc0 += t5.x * __uint_as_float(u5 << 16);
            acc1 += t5.x * __uint_as_float(u5 & 0xffff0000u);
            acc0 += t6.x * __uint_as_float(u6 << 16);
            acc1 += t6.x * __uint_as_float(u6 & 0xffff0000u);
            acc0 += t7.x * __uint_as_float(u7 << 16);
            acc1 += t7.x * __uint_as_float(u7 & 0xffff0000u);
        }
    }
    for (int off = 32; off > 0; off >>= 1) efl += __shfl_xor(efl, off);
    const float aggr = efl / adj_row[wid];
    const float dg = degree[wid];
    const float2 inn = *(const float2*)(input + (size_t)wid * F_IN + 2 * lane);
    float2 o;
    o.x = acc0 * dg + (1.f - aggr) * inn.x;
    o.y = acc1 * dg + (1.f - aggr) * inn.y;
    *(float2*)(out_h + (size_t)wid * F_IN + 2 * lane) = o;
}

extern "C" void kernel_launch(void* const* d_in, const int* in_sizes, int n_in,
                              void* d_out, int out_size, void* d_ws, size_t ws_size,
                              hipStream_t stream) {
    const float* input   = (const float*)d_in[0];
    const int*   edges   = (const int*)  d_in[1];
    const float* adj_row = (const float*)d_in[3];
    const float* degree  = (const float*)d_in[4];
    const float* w_mini  = (const float*)d_in[5];
    const float* b_mini  = (const float*)d_in[6];
    const float* ab      = (const float*)d_in[7];
    const float* lf1_w   = (const float*)d_in[8];
    const float* lf1_b   = (const float*)d_in[9];
    const float* lf2_w   = (const float*)d_in[10];
    const float* lf2_b   = (const float*)d_in[11];

    const int N = in_sizes[0] / F_IN;
    const int E = in_sizes[1] / 2;
    const int NB1 = (N + 255) >> 8;
    const int* src = edges;
    const int* dst = edges + E;

    float* final_h = (float*)d_out;
    float* ef_out  = (float*)d_out + (size_t)N * F_IN;

    // workspace layout (~59 MB)
    unsigned short* hb  = (unsigned short*)d_ws;               // N*16 bf16
    unsigned short* fcb = hb + (size_t)N * AH;                 // E bf16 (fc1)
    float* factor  = (float*)((((uintptr_t)(fcb + E)) + 15) & ~(uintptr_t)15); // N
    float* fc0_sum = factor + N;                               // N  \ memset
    int*   cnt     = (int*)(fc0_sum + N);                      // N  / together
    int*   row_ofs = cnt + N;                                  // N (starts -> ends)
    float* Cj      = (float*)(row_ofs + N);                    // 16
    int*   bsum    = (int*)(Cj + 16);                          // 1024
    int*   bucket_base = bsum + 1024;                          // NB1+1
    int*   bucket_cur  = bucket_base + NB1 + 1;                // NB1
    unsigned long long* rec =
        (unsigned long long*)((((uintptr_t)(bucket_cur + NB1)) + 15) & ~(uintptr_t)15); // E
    unsigned long long* rec2 = rec + E;                        // E
    unsigned* sim = (unsigned*)(rec2 + E);                     // N*64 bf16 pairs

    hipMemsetAsync(fc0_sum, 0, (size_t)2 * N * sizeof(float), stream);

    k_mini<<<(N + 15) / 16, 256, 0, stream>>>(input, w_mini, b_mini, degree, hb, sim, N);
    k_prep<<<1, 64, 0, stream>>>(lf1_w, ab, Cj);
    k_hist<<<(E + 255) / 256, 256, 0, stream>>>(src, cnt, E);
    {
        const int nb = (N + SCAN_B * SCAN_I - 1) / (SCAN_B * SCAN_I);
        k_scan_part<<<nb, SCAN_B, 0, stream>>>(cnt, row_ofs, bsum, N);
        k_scan_tops<<<1, SCAN_B, 0, stream>>>(bsum, nb);
        k_scan_add<<<(N + 255) / 256, 256, 0, stream>>>(row_ofs, bsum, N);
    }
    k_binit<<<(NB1 + 256) / 256, 256, 0, stream>>>(row_ofs, bucket_base, bucket_cur, NB1, N, E);
    k_mlp<<<(E + 255) / 256, 256, 0, stream>>>(src, dst, hb,
                                               lf1_w, lf1_b, lf2_w, lf2_b, Cj,
                                               fc0_sum, fcb, E);
    k_factor<<<(N + 255) / 256, 256, 0, stream>>>(fc0_sum, cnt, factor, N);
    k_part1<<<(E + TILE - 1) / TILE, 256, 0, stream>>>(src, dst, fcb, factor,
                                                       bucket_cur, rec, ef_out, E, NB1);
    k_part2<<<NB1, 256, 0, stream>>>(bucket_base, row_ofs, rec, rec2);
    k_spmm_final<<<(N * 64 + 255) / 256, 256, 0, stream>>>(row_ofs, cnt, rec2, factor, sim,
                                                           input, degree, adj_row, final_h, N);
}